// Round 3
// baseline (215.141 us; speedup 1.0000x reference)
//
#include <hip/hip_runtime.h>
#include <hip/hip_bf16.h>

#define I_DIM  512
#define O_DIM  512
#define NBATCH 1024
#define NSPL   8            // spline coeffs per input channel
#define KPI    12           // K slots per channel: 8 spline + s_hi,s_hi,s_lo,0
#define KDIM   (I_DIM * KPI)   // 6144
#define NGRID  12           // extended grid points per channel
#define SPLITK 16

typedef __attribute__((ext_vector_type(8))) short bf16x8;
typedef __attribute__((ext_vector_type(4))) float f32x4;

// async global->LDS 16B: per-lane source, wave-uniform LDS base (+lane*16 in HW)
__device__ __forceinline__ void gload_lds16(const __hip_bfloat16* g, __hip_bfloat16* l) {
    __builtin_amdgcn_global_load_lds(
        (const __attribute__((address_space(1))) void*)g,
        (__attribute__((address_space(3))) void*)l, 16, 0, 0);
}

// ---------------------------------------------------------------------------
// Wt row build: slots 0..7 = sp*coef[k]; 8=hi(sb); 9=lo(sb); 10=hi(sb); 11=0.
// Pairs with features [B0..B7, s_hi, s_hi, s_lo, 0]:
//   s_hi*w_hi + s_hi*w_lo + s_lo*w_hi ~= s*sb   (rel err ~2^-17)
// ---------------------------------------------------------------------------
__device__ __forceinline__ void wt_core(const float* __restrict__ coef,
                                        const float* __restrict__ sb,
                                        const float* __restrict__ sp,
                                        __hip_bfloat16* __restrict__ W, int tid) {
    int i = tid & (I_DIM - 1);
    int o = tid >> 9;
    float sbv = sb[i * O_DIM + o];
    float spv = sp[i * O_DIM + o];
    const float* cf = coef + (size_t)(i * O_DIM + o) * NSPL;
    __align__(16) __hip_bfloat16 row[KPI];
#pragma unroll
    for (int k = 0; k < NSPL; ++k) row[k] = __float2bfloat16(spv * cf[k]);
    __hip_bfloat16 whi = __float2bfloat16(sbv);
    __hip_bfloat16 wlo = __float2bfloat16(sbv - __bfloat162float(whi));
    row[8]  = whi;
    row[9]  = wlo;
    row[10] = whi;
    row[11] = __float2bfloat16(0.0f);
    uint2* dst = (uint2*)(W + (size_t)o * KDIM + i * KPI);
    const uint2* src = (const uint2*)row;
    dst[0] = src[0]; dst[1] = src[1]; dst[2] = src[2];
}

__device__ __forceinline__ void features_core(float xv, const float* __restrict__ grid,
                                              int i, __hip_bfloat16* __restrict__ dst) {
    float g[NGRID];
#pragma unroll
    for (int j = 0; j < NGRID; ++j) g[j] = grid[i * NGRID + j];

    float B[NGRID - 1];
#pragma unroll
    for (int j = 0; j < NGRID - 1; ++j)
        B[j] = (xv >= g[j] && xv < g[j + 1]) ? 1.0f : 0.0f;
#pragma unroll
    for (int p = 1; p <= 3; ++p) {
#pragma unroll
        for (int j = 0; j < NGRID - 1 - p; ++j) {
            B[j] = (xv - g[j]) / (g[j + p] - g[j]) * B[j]
                 + (g[j + p + 1] - xv) / (g[j + p + 1] - g[j + 1]) * B[j + 1];
        }
    }
    float s = xv / (1.0f + __expf(-xv));  // silu
    __hip_bfloat16 shi = __float2bfloat16(s);
    __hip_bfloat16 slo = __float2bfloat16(s - __bfloat162float(shi));

    __align__(16) __hip_bfloat16 row[KPI];
#pragma unroll
    for (int k = 0; k < NSPL; ++k) row[k] = __float2bfloat16(B[k]);
    row[8]  = shi;
    row[9]  = shi;
    row[10] = slo;
    row[11] = __float2bfloat16(0.0f);

    uint2* d = (uint2*)dst;
    const uint2* srow = (const uint2*)row;
    d[0] = srow[0]; d[1] = srow[1]; d[2] = srow[2];
}

// ---------------------------------------------------------------------------
// Fused prep: blocks [0,3072) build Wt for all 3 layers; [3072,5120) build
// layer-0 features from x. Independent jobs, one launch.
// ---------------------------------------------------------------------------
__global__ void prep_kernel(const float* __restrict__ c0, const float* __restrict__ b0, const float* __restrict__ p0,
                            const float* __restrict__ c1, const float* __restrict__ b1, const float* __restrict__ p1,
                            const float* __restrict__ c2, const float* __restrict__ b2, const float* __restrict__ p2,
                            __hip_bfloat16* __restrict__ Wt,
                            const float* __restrict__ x, const float* __restrict__ grid0,
                            __hip_bfloat16* __restrict__ F) {
    if (blockIdx.x < 3072) {
        int l = blockIdx.x / 1024;  // 1024 blocks x 256 threads = 512*512 per layer
        const float* coef = l == 0 ? c0 : (l == 1 ? c1 : c2);
        const float* sb   = l == 0 ? b0 : (l == 1 ? b1 : b2);
        const float* sp   = l == 0 ? p0 : (l == 1 ? p1 : p2);
        int tid = (blockIdx.x - l * 1024) * 256 + threadIdx.x;
        wt_core(coef, sb, sp, Wt + (size_t)l * O_DIM * KDIM, tid);
    } else {
        int tid = (blockIdx.x - 3072) * 256 + threadIdx.x;  // b*512+i
        features_core(x[tid], grid0, tid & (I_DIM - 1), F + (size_t)tid * KPI);
    }
}

// splitK-partial sum fused into next layer's feature build
__global__ void build_features_sum(const float* __restrict__ P,  // [SPLITK][NBATCH*I_DIM]
                                   const float* __restrict__ grid,
                                   __hip_bfloat16* __restrict__ F) {
    int tid = blockIdx.x * blockDim.x + threadIdx.x;
    float xv = 0.f;
#pragma unroll
    for (int s = 0; s < SPLITK; ++s) xv += P[(size_t)s * NBATCH * I_DIM + tid];
    features_core(xv, grid, tid & (I_DIM - 1), F + (size_t)tid * KPI);
}

__global__ void reduce_out(const float* __restrict__ P, float* __restrict__ out) {
    int tid = blockIdx.x * blockDim.x + threadIdx.x;
    float v = 0.f;
#pragma unroll
    for (int s = 0; s < SPLITK; ++s) v += P[(size_t)s * NBATCH * O_DIM + tid];
    out[tid] = v;
}

// ---------------------------------------------------------------------------
// GEMM: P[ks][b,o] = sum_{k in seg} F[b,k] * Wt[o][k]   (bf16 MFMA, fp32 acc)
// 128x128 tile, BK=64, 4 waves each computing a 64x64 quadrant (4x4 of
// 16x16x32 -> 32 MFMAs per wave per K-round). global_load_lds width-16 with
// XOR-swizzled chunk placement (pos = chunk ^ (row&7)): ds_read_b128 lands at
// 2-way bank aliasing only (free, m136). splitK=16 -> dim3(8,4,16)=512 blocks
// = 2 blocks/CU. Plain stores; splitK reduction fused downstream.
// ---------------------------------------------------------------------------
#define BM 128
#define BN 128
#define BK 64                  // bf16 per row = 128 B = 8 chunks of 16 B
#define KSEG (KDIM / SPLITK)   // 384 -> 6 K-rounds

__global__ __launch_bounds__(256)
void gemm_kernel(const __hip_bfloat16* __restrict__ A,   // [NBATCH][KDIM]
                 const __hip_bfloat16* __restrict__ Wt,  // [O_DIM][KDIM]
                 float* __restrict__ P) {                // [SPLITK][NBATCH][O_DIM]
    __shared__ __hip_bfloat16 lA[BM * BK];   // 16 KB
    __shared__ __hip_bfloat16 lB[BN * BK];   // 16 KB

    int bm = blockIdx.x;        // 0..7
    int bn = blockIdx.y;        // 0..3
    int ks = blockIdx.z;        // 0..15
    int tid = threadIdx.x;
    int lane = tid & 63;
    int wave = tid >> 6;
    int wr = (wave & 1) * 64;   // wave quadrant in tile
    int wc = (wave >> 1) * 64;
    int q  = lane >> 4;         // 0..3
    int ln = lane & 15;

    f32x4 acc[4][4];
#pragma unroll
    for (int a = 0; a < 4; ++a)
#pragma unroll
        for (int b = 0; b < 4; ++b) acc[a][b] = (f32x4){0.f, 0.f, 0.f, 0.f};

    const __hip_bfloat16* Abase = A  + (size_t)(bm * BM) * KDIM + ks * KSEG;
    const __hip_bfloat16* Bbase = Wt + (size_t)(bn * BN) * KDIM + ks * KSEG;

    // staging: 1024 16B-chunks per tile (128 rows x 8). 4 calls x 4 waves x 64
    // lanes. chunk cc -> row r = cc>>3, pos jp = cc&7, source chunk j = jp^(r&7).
    int ccw[4], rr[4], jj[4];
#pragma unroll
    for (int c = 0; c < 4; ++c) {
        int cc = c * 256 + tid;           // = c*256 + wave*64 + lane
        ccw[c] = c * 256 + wave * 64;     // wave-uniform LDS chunk base
        rr[c] = cc >> 3;
        jj[c] = (cc & 7) ^ (rr[c] & 7);
    }

    for (int kt = 0; kt < KSEG; kt += BK) {
        __syncthreads();
#pragma unroll
        for (int c = 0; c < 4; ++c)
            gload_lds16(Abase + (size_t)rr[c] * KDIM + kt + jj[c] * 8, lA + ccw[c] * 8);
#pragma unroll
        for (int c = 0; c < 4; ++c)
            gload_lds16(Bbase + (size_t)rr[c] * KDIM + kt + jj[c] * 8, lB + ccw[c] * 8);
        __syncthreads();

#pragma unroll
        for (int kh = 0; kh < 2; ++kh) {
            bf16x8 af[4], bf[4];
#pragma unroll
            for (int rt = 0; rt < 4; ++rt) {
                int row = wr + rt * 16 + ln;
                af[rt] = *(const bf16x8*)(lA + row * BK + (((kh * 4 + q) ^ (row & 7)) * 8));
            }
#pragma unroll
            for (int ct = 0; ct < 4; ++ct) {
                int row = wc + ct * 16 + ln;
                bf[ct] = *(const bf16x8*)(lB + row * BK + (((kh * 4 + q) ^ (row & 7)) * 8));
            }
#pragma unroll
            for (int rt = 0; rt < 4; ++rt)
#pragma unroll
                for (int ct = 0; ct < 4; ++ct)
                    acc[rt][ct] = __builtin_amdgcn_mfma_f32_16x16x32_bf16(
                        af[rt], bf[ct], acc[rt][ct], 0, 0, 0);
        }
    }

    // epilogue: C/D layout col = lane&15, row = quad*4 + reg (round-0 verified)
    float* Pp = P + (size_t)ks * NBATCH * O_DIM;
    int orow = bm * BM + wr;
    int ocol = bn * BN + wc + ln;
#pragma unroll
    for (int rt = 0; rt < 4; ++rt)
#pragma unroll
        for (int ct = 0; ct < 4; ++ct)
#pragma unroll
            for (int r = 0; r < 4; ++r)
                Pp[(size_t)(orow + rt * 16 + q * 4 + r) * O_DIM + ocol + ct * 16]
                    = acc[rt][ct][r];
}

// ---------------------------------------------------------------------------
extern "C" void kernel_launch(void* const* d_in, const int* in_sizes, int n_in,
                              void* d_out, int out_size, void* d_ws, size_t ws_size,
                              hipStream_t stream) {
    const float* x0      = (const float*)d_in[0];
    const float* grid[3] = {(const float*)d_in[1], (const float*)d_in[5], (const float*)d_in[9]};
    const float* coef[3] = {(const float*)d_in[2], (const float*)d_in[6], (const float*)d_in[10]};
    const float* sb[3]   = {(const float*)d_in[3], (const float*)d_in[7], (const float*)d_in[11]};
    const float* sp[3]   = {(const float*)d_in[4], (const float*)d_in[8], (const float*)d_in[12]};

    char* ws = (char*)d_ws;
    const size_t wt_bytes = (size_t)O_DIM * KDIM * sizeof(__hip_bfloat16);   // 6.3 MB/layer
    const size_t f_bytes  = (size_t)NBATCH * KDIM * sizeof(__hip_bfloat16);  // 12.6 MB
    __hip_bfloat16* Wt = (__hip_bfloat16*)ws;                  // 3 layers contiguous
    __hip_bfloat16* F  = (__hip_bfloat16*)(ws + 3 * wt_bytes);
    float* P = (float*)(ws + 3 * wt_bytes + f_bytes);          // [16][1024][512] = 33.6 MB

    prep_kernel<<<5120, 256, 0, stream>>>(
        coef[0], sb[0], sp[0], coef[1], sb[1], sp[1], coef[2], sb[2], sp[2],
        Wt, x0, grid[0], F);
    gemm_kernel<<<dim3(8, 4, SPLITK), 256, 0, stream>>>(F, Wt, P);

    for (int l = 1; l < 3; ++l) {
        build_features_sum<<<(NBATCH * I_DIM) / 256, 256, 0, stream>>>(P, grid[l], F);
        gemm_kernel<<<dim3(8, 4, SPLITK), 256, 0, stream>>>(F, Wt + (size_t)l * O_DIM * KDIM, P);
    }
    reduce_out<<<(NBATCH * O_DIM) / 256, 256, 0, stream>>>(P, (float*)d_out);
}